// Round 7
// baseline (189.587 us; speedup 1.0000x reference)
//
#include <hip/hip_runtime.h>
#include <math.h>

// Round 8b: full-row waves. One wave owns entire 512-px rows (8 px/lane via
// two float4 quads: A at x=4*lane, B at x=256+4*lane). Row reads are 3x2KB
// fully sequential float4 loads (16B/lane); stores are 2KB rows. x-neighbor
// exchange via DPP wave rotates; seam lane63<->lane0 via rotate+cndmask;
// image x-boundaries via shift-in-zero / reflect / clamp selects.
// Fix vs R8: DPP ctrl must be a compile-time immediate -> template param.
#define IMW 512
#define SEG 8
#define NSEG 64    // 512/SEG

template<int CTRL>
__device__ __forceinline__ float dpp_mov(float v) {
    return __int_as_float(__builtin_amdgcn_update_dpp(
        0, __float_as_int(v), CTRL, 0xF, 0xF, true));
}
#define ROTR1(v) dpp_mov<0x13C>(v)   // wave_ror:1  lane i <- (i-1)&63
#define SHR1(v)  dpp_mov<0x138>(v)   // wave_shr:1  lane i <- i-1, lane0 <- 0
#define ROTL1(v) dpp_mov<0x134>(v)   // wave_rol:1  lane i <- (i+1)&63
#define SHL1(v)  dpp_mov<0x130>(v)   // wave_shl:1  lane i <- i+1, lane63 <- 0

__device__ __forceinline__ int reflect512(int i) {   // valid for i in [-511,1022]
    int a = i < 0 ? -i : i;
    int b = 1022 - a;
    return a < b ? a : b;
}

struct CT { static constexpr bool value = true;  };
struct CF { static constexpr bool value = false; };

template<bool EDGE>
__device__ __forceinline__ void run_rows(
    const float* b0, const float* b1, const float* b2, float* ob,
    const int Y0, const int Y1, const int lane)
{
    const float K0 = 0.054488684549643f, K1 = 0.244201342003233f,
                K2 = 0.402619946931554f;
    const bool l0  = (lane == 0);
    const bool l63 = (lane == 63);
    const int  vo  = lane * 4;                 // float offset of quad A

    // rings; row labels at iteration v (after push):
    float hb[5][8];                 // h-blur rows v-4..v
    float hx[3][8], hy[3][8];       // sobel h-passes rows v-4..v-2
    float mg[3][8];                 // magnitude rows v-5..v-3
    int   ax[2][8];                 // axis rows v-4, v-3
    float cm[5][8];                 // colmax rows v-8..v-4
    #pragma unroll
    for (int r = 0; r < 5; ++r) {
        #pragma unroll
        for (int e = 0; e < 8; ++e) { hb[r][e] = 0.f; cm[r][e] = 0.f; }
    }
    #pragma unroll
    for (int r = 0; r < 3; ++r) {
        #pragma unroll
        for (int e = 0; e < 8; ++e) { hx[r][e] = 0.f; hy[r][e] = 0.f; mg[r][e] = 0.f; }
    }
    #pragma unroll
    for (int r = 0; r < 2; ++r) {
        #pragma unroll
        for (int e = 0; e < 8; ++e) ax[r][e] = 0;
    }

    // prefetch row Y0-6 (pointers already at its reflected position)
    float4 c0A = *(const float4*)(b0 + vo), c0B = *(const float4*)(b0 + 256 + vo);
    float4 c1A = *(const float4*)(b1 + vo), c1B = *(const float4*)(b1 + 256 + vo);
    float4 c2A = *(const float4*)(b2 + vo), c2B = *(const float4*)(b2 + 256 + vo);

    auto iter = [&](int v, auto st) {
        constexpr bool STORE = decltype(st)::value;

        // ---- [1] gray row v from in-flight regs
        float gA[4] = {
            0.299f*c2A.x + 0.587f*c1A.x + 0.114f*c0A.x,
            0.299f*c2A.y + 0.587f*c1A.y + 0.114f*c0A.y,
            0.299f*c2A.z + 0.587f*c1A.z + 0.114f*c0A.z,
            0.299f*c2A.w + 0.587f*c1A.w + 0.114f*c0A.w };
        float gB[4] = {
            0.299f*c2B.x + 0.587f*c1B.x + 0.114f*c0B.x,
            0.299f*c2B.y + 0.587f*c1B.y + 0.114f*c0B.y,
            0.299f*c2B.z + 0.587f*c1B.z + 0.114f*c0B.z,
            0.299f*c2B.w + 0.587f*c1B.w + 0.114f*c0B.w };

        // ---- issue loads for row v+1 (reflect walk is +-1 row)
        {
            int d;
            if constexpr (EDGE) d = ((unsigned)v <= 510u) ? IMW : -IMW;
            else                d = IMW;
            b0 += d; b1 += d; b2 += d;
        }
        c0A = *(const float4*)(b0 + vo); c0B = *(const float4*)(b0 + 256 + vo);
        c1A = *(const float4*)(b1 + vo); c1B = *(const float4*)(b1 + 256 + vo);
        c2A = *(const float4*)(b2 + vo); c2B = *(const float4*)(b2 + 256 + vo);

        // ---- [2] h-blur row v (x reflect: g(-1)=g(1), g(-2)=g(2), g(512)=g(510), g(513)=g(509))
        {
            float rAe2 = ROTR1(gA[2]), rAe3 = ROTR1(gA[3]);
            float rBe2 = ROTR1(gB[2]), rBe3 = ROTR1(gB[3]);
            float lAe0 = ROTL1(gA[0]), lAe1 = ROTL1(gA[1]);
            float lBe0 = ROTL1(gB[0]), lBe1 = ROTL1(gB[1]);
            float Am1 = l0  ? gA[1] : rAe3;    // x-1 of quad A
            float Am2 = l0  ? gA[2] : rAe2;    // x-2
            float Bm1 = l0  ? rAe3  : rBe3;    // seam x=255
            float Bm2 = l0  ? rAe2  : rBe2;    // seam x=254
            float Ap1 = l63 ? lBe0  : lAe0;    // seam x=256
            float Ap2 = l63 ? lBe1  : lAe1;    // seam x=257
            float Bp1 = l63 ? gB[2] : lBe0;    // reflect g(512)=g(510)
            float Bp2 = l63 ? gB[1] : lBe1;    // reflect g(513)=g(509)
            float nh[8] = {
                K0*(Am2  +gA[2]) + K1*(Am1  +gA[1]) + K2*gA[0],
                K0*(Am1  +gA[3]) + K1*(gA[0]+gA[2]) + K2*gA[1],
                K0*(gA[0]+Ap1  ) + K1*(gA[1]+gA[3]) + K2*gA[2],
                K0*(gA[1]+Ap2  ) + K1*(gA[2]+Ap1  ) + K2*gA[3],
                K0*(Bm2  +gB[2]) + K1*(Bm1  +gB[1]) + K2*gB[0],
                K0*(Bm1  +gB[3]) + K1*(gB[0]+gB[2]) + K2*gB[1],
                K0*(gB[0]+Bp1  ) + K1*(gB[1]+gB[3]) + K2*gB[2],
                K0*(gB[1]+Bp2  ) + K1*(gB[2]+Bp1  ) + K2*gB[3] };
            #pragma unroll
            for (int r = 0; r < 4; ++r) {
                #pragma unroll
                for (int e = 0; e < 8; ++e) hb[r][e] = hb[r+1][e];
            }
            #pragma unroll
            for (int e = 0; e < 8; ++e) hb[4][e] = nh[e];
        }

        // ---- [3] v-blur -> blur row v-2; [4] sobel h-pass (x edge-clamp)
        {
            float bl[8];
            #pragma unroll
            for (int e = 0; e < 8; ++e)
                bl[e] = K0*(hb[0][e]+hb[4][e]) + K1*(hb[1][e]+hb[3][e]) + K2*hb[2][e];
            float rA3 = ROTR1(bl[3]), rB3 = ROTR1(bl[7]);
            float lA0 = ROTL1(bl[0]), lB0 = ROTL1(bl[4]);
            float sAm1 = l0  ? bl[0] : rA3;    // clamp b(-1)=b(0)
            float sBm1 = l0  ? rA3   : rB3;    // seam
            float sAp1 = l63 ? lB0   : lA0;    // seam
            float sBp1 = l63 ? bl[7] : lB0;    // clamp b(512)=b(511)
            float nx[8] = { bl[1]-sAm1, bl[2]-bl[0], bl[3]-bl[1], sAp1-bl[2],
                            bl[5]-sBm1, bl[6]-bl[4], bl[7]-bl[5], sBp1-bl[6] };
            float ny[8] = { sAm1+2.f*bl[0]+bl[1], bl[0]+2.f*bl[1]+bl[2],
                            bl[1]+2.f*bl[2]+bl[3], bl[2]+2.f*bl[3]+sAp1,
                            sBm1+2.f*bl[4]+bl[5], bl[4]+2.f*bl[5]+bl[6],
                            bl[5]+2.f*bl[6]+bl[7], bl[6]+2.f*bl[7]+sBp1 };
            #pragma unroll
            for (int r = 0; r < 2; ++r) {
                #pragma unroll
                for (int e = 0; e < 8; ++e) { hx[r][e] = hx[r+1][e]; hy[r][e] = hy[r+1][e]; }
            }
            #pragma unroll
            for (int e = 0; e < 8; ++e) { hx[2][e] = nx[e]; hy[2][e] = ny[e]; }
        }

        // ---- [5] sobel v-pass at g = v-3 -> mag/axis; push rings
        {
            const int g = v - 3;
            float nmg[8]; int nax[8];
            #pragma unroll
            for (int e = 0; e < 8; ++e) {
                float hxa, hxc, hya, hyc;
                if constexpr (EDGE) {
                    hxa = (g==0)   ? hx[1][e] : hx[0][e];
                    hxc = (g==511) ? hx[1][e] : hx[2][e];
                    hya = (g==0)   ? hy[1][e] : hy[0][e];
                    hyc = (g==511) ? hy[1][e] : hy[2][e];
                } else {
                    hxa = hx[0][e]; hxc = hx[2][e]; hya = hy[0][e]; hyc = hy[2][e];
                }
                float gx = (hxa + 2.f*hx[1][e] + hxc) * 0.125f;
                float gy = (hyc - hya) * 0.125f;
                float mag = sqrtf(gx*gx + gy*gy + 1e-6f);
                float axm = fabsf(gx), aym = fabsf(gy);
                int a;
                if (aym <= 0.41421356237309515f * axm)      a = 0;
                else if (aym >= 2.4142135623730951f * axm)  a = 2;
                else a = ((gx >= 0.f) == (gy >= 0.f)) ? 1 : 3;
                nmg[e] = mag; nax[e] = a;
            }
            #pragma unroll
            for (int r = 0; r < 2; ++r) {
                #pragma unroll
                for (int e = 0; e < 8; ++e) mg[r][e] = mg[r+1][e];
            }
            #pragma unroll
            for (int e = 0; e < 8; ++e) { mg[2][e] = nmg[e]; ax[0][e] = ax[1][e]; ax[1][e] = nax[e]; }
        }

        // ---- [6] NMS at m = v-4 (x zero-pad) + [7] colmax (x zero-pad +-2)
        {
            float M0[8], M2[8];
            if constexpr (EDGE) {
                const int m = v - 4;
                #pragma unroll
                for (int e = 0; e < 8; ++e) {
                    M0[e] = (m==0)   ? 0.f : mg[0][e];
                    M2[e] = (m==511) ? 0.f : mg[2][e];
                }
            } else {
                #pragma unroll
                for (int e = 0; e < 8; ++e) { M0[e] = mg[0][e]; M2[e] = mg[2][e]; }
            }
            float M0l[8], M0r[8], M1l[8], M1r[8], M2l[8], M2r[8];
            auto make_ins = [&](const float* R, float* Lv, float* Rv) {
                float ra3 = ROTR1(R[3]), rb3 = ROTR1(R[7]);
                float la0 = ROTL1(R[0]), lb0 = ROTL1(R[4]);
                float shA = SHR1(R[3]);            // A left, 0 at x=0
                float shB = SHL1(R[4]);            // B right, 0 at x=511
                float mB  = l0  ? ra3 : rb3;       // seam x=255
                float pA  = l63 ? lb0 : la0;       // seam x=256
                Lv[0]=shA;  Lv[1]=R[0]; Lv[2]=R[1]; Lv[3]=R[2];
                Lv[4]=mB;   Lv[5]=R[4]; Lv[6]=R[5]; Lv[7]=R[6];
                Rv[0]=R[1]; Rv[1]=R[2]; Rv[2]=R[3]; Rv[3]=pA;
                Rv[4]=R[5]; Rv[5]=R[6]; Rv[6]=R[7]; Rv[7]=shB;
            };
            make_ins(M0,    M0l, M0r);
            make_ins(mg[1], M1l, M1r);
            make_ins(M2,    M2l, M2r);

            float msk[8];
            #pragma unroll
            for (int e = 0; e < 8; ++e) {
                const int d = ax[0][e];
                float c  = mg[1][e];
                float mp = (d==0) ? M1r[e] : (d==1) ? M2r[e] : (d==2) ? M2[e] : M2l[e];
                float mn = (d==0) ? M1l[e] : (d==1) ? M0l[e] : (d==2) ? M0[e] : M0r[e];
                msk[e] = (fminf(c - mp, c - mn) > 0.f) ? c : 0.f;
            }

            // colmax: taps x-2..x+2, zero-pad, seam-wrapped
            float cr2 = ROTR1(msk[2]), cr3 = ROTR1(msk[3]);
            float dr2 = ROTR1(msk[6]), dr3 = ROTR1(msk[7]);
            float el0 = ROTL1(msk[0]), el1 = ROTL1(msk[1]);
            float fl0 = ROTL1(msk[4]), fl1 = ROTL1(msk[5]);
            float sA2 = SHR1(msk[2]),  sA3 = SHR1(msk[3]);
            float tB0 = SHL1(msk[4]),  tB1 = SHL1(msk[5]);
            float Am2 = sA2, Am1 = sA3;
            float Bm2 = l0  ? cr2 : dr2, Bm1 = l0  ? cr3 : dr3;
            float Ap1 = l63 ? fl0 : el0, Ap2 = l63 ? fl1 : el1;
            float Bp1 = tB0, Bp2 = tB1;
            float ncm[8] = {
                fmaxf(fmaxf(fmaxf(Am1,    msk[1]), fmaxf(Am2,    msk[2])), msk[0]),
                fmaxf(fmaxf(fmaxf(msk[0], msk[2]), fmaxf(Am1,    msk[3])), msk[1]),
                fmaxf(fmaxf(fmaxf(msk[1], msk[3]), fmaxf(msk[0], Ap1   )), msk[2]),
                fmaxf(fmaxf(fmaxf(msk[2], Ap1   ), fmaxf(msk[1], Ap2   )), msk[3]),
                fmaxf(fmaxf(fmaxf(Bm1,    msk[5]), fmaxf(Bm2,    msk[6])), msk[4]),
                fmaxf(fmaxf(fmaxf(msk[4], msk[6]), fmaxf(Bm1,    msk[7])), msk[5]),
                fmaxf(fmaxf(fmaxf(msk[5], msk[7]), fmaxf(msk[4], Bp1   )), msk[6]),
                fmaxf(fmaxf(fmaxf(msk[6], Bp1   ), fmaxf(msk[5], Bp2   )), msk[7]) };
            #pragma unroll
            for (int r = 0; r < 4; ++r) {
                #pragma unroll
                for (int e = 0; e < 8; ++e) cm[r][e] = cm[r+1][e];
            }
            #pragma unroll
            for (int e = 0; e < 8; ++e) cm[4][e] = ncm[e];
        }

        // ---- [8] out row y = v-6 (vertical 5-max, y zero-pad)
        if constexpr (STORE) {
            const int y = v - 6;
            bool go = true;
            if constexpr (EDGE) go = (y >= Y0);
            if (go) {
                float o[8];
                #pragma unroll
                for (int e = 0; e < 8; ++e) {
                    float c0 = cm[0][e], c1 = cm[1][e], c3 = cm[3][e], c4 = cm[4][e];
                    if constexpr (EDGE) {
                        c0 = (y>=2)   ? c0 : 0.f;
                        c1 = (y>=1)   ? c1 : 0.f;
                        c3 = (y<=510) ? c3 : 0.f;
                        c4 = (y<=509) ? c4 : 0.f;
                    }
                    o[e] = fmaxf(fmaxf(fmaxf(c0, c1), fmaxf(cm[2][e], c3)), c4);
                }
                float* orow = ob + (size_t)y * IMW;
                float4 t0; t0.x=o[0]; t0.y=o[1]; t0.z=o[2]; t0.w=o[3];
                float4 t1; t1.x=o[4]; t1.y=o[5]; t1.z=o[6]; t1.w=o[7];
                *(float4*)(orow + vo)       = t0;
                *(float4*)(orow + 256 + vo) = t1;
            }
        }
    };

    if constexpr (EDGE) {
        #pragma unroll 2
        for (int v = Y0 - 6; v < Y1 + 6; ++v) iter(v, CT{});
    } else {
        #pragma unroll 4
        for (int v = Y0 - 6; v < Y0 + 6; ++v) iter(v, CF{});   // 12-row warmup
        #pragma unroll 4
        for (int v = Y0 + 6; v < Y1 + 6; ++v) iter(v, CT{});   // SEG stores
    }
}

__global__ __launch_bounds__(256, 2)
void canny_row(const float* __restrict__ x, float* __restrict__ out) {
    const int lane = threadIdx.x & 63;
    const int b = blockIdx.x;
    // XCD-contiguous swizzle: 64 consecutive logical blocks (= 4 whole images)
    // per XCD for halo L2 reuse. 512 blocks = 8 * 64, bijective.
    const int l = ((b & 7) << 6) + (b >> 3);
    const int unit = __builtin_amdgcn_readfirstlane(l * 4 + (int)(threadIdx.x >> 6));
    const int img = unit >> 6;
    const int seg = unit & 63;
    const int Y0 = seg * SEG, Y1 = Y0 + SEG;

    const float* base = x + (size_t)img * 3 * IMW * IMW;
    const float* b0 = base + (size_t)reflect512(Y0 - 6) * IMW;
    const float* b1 = b0 + (size_t)IMW * IMW;
    const float* b2 = b0 + (size_t)2 * IMW * IMW;
    float* ob = out + (size_t)img * IMW * IMW;

    if (seg == 0 || seg == NSEG - 1)
        run_rows<true >(b0, b1, b2, ob, Y0, Y1, lane);
    else
        run_rows<false>(b0, b1, b2, ob, Y0, Y1, lane);
}

extern "C" void kernel_launch(void* const* d_in, const int* in_sizes, int n_in,
                              void* d_out, int out_size, void* d_ws, size_t ws_size,
                              hipStream_t stream) {
    const float* x = (const float*)d_in[0];
    float* out = (float*)d_out;
    const int units = 32 * NSEG;            // 2048 waves
    dim3 grid(units / 4);                   // 512 blocks of 4 waves
    canny_row<<<grid, 256, 0, stream>>>(x, out);
}